// Round 1
// baseline (5968.881 us; speedup 1.0000x reference)
//
#include <hip/hip_runtime.h>

#define NPTS 80000
#define MPTS 150000
#define NDPTS 10000
#define KOFF 27
#define C3 16
#define CP 259
#define C2 64
#define CM 80
#define CO 96

// ---------------------------------------------------------------------------
// Kernel 1: conv3d (Cin=Cout=16) + bn_relu. Writes y3d AND mix[:, :16]
// (fuses the later concat). 16 rows per 256-thread block; W3d fully in LDS.
// ---------------------------------------------------------------------------
__global__ __launch_bounds__(256) void conv3d_bnrelu_kernel(
    const float* __restrict__ x3d, const int* __restrict__ nbr,
    const float* __restrict__ W3d, const float* __restrict__ g3d,
    const float* __restrict__ b3d, float* __restrict__ y3d,
    float* __restrict__ mix)
{
  __shared__ float wS[KOFF * C3 * C3];   // 27.6 KB
  __shared__ float fS[16][C3];
  const int tid = threadIdx.x;
  const int base = blockIdx.x * 16;
  for (int e = tid; e < KOFF * C3 * C3; e += 256) wS[e] = W3d[e];
  const int r = tid >> 4, c = tid & 15;
  const int row = base + r;
  float acc = 0.f;
  for (int k = 0; k < KOFF; ++k) {
    int idx = nbr[row * KOFF + k];                 // 16 lanes same addr: L1 broadcast
    float fv = (idx >= 0) ? x3d[idx * C3 + c] : 0.f;
    __syncthreads();                               // prev-iter readers done
    fS[r][c] = fv;
    __syncthreads();
    const float* wk = &wS[k * C3 * C3];
    #pragma unroll
    for (int ci = 0; ci < C3; ++ci)
      acc = fmaf(fS[r][ci], wk[ci * C3 + c], acc);
  }
  float v = fmaxf(fmaf(acc, g3d[c], b3d[c]), 0.f);
  y3d[row * C3 + c] = v;
  mix[row * CM + c] = v;
}

// ---------------------------------------------------------------------------
// Kernel 2: fused  gate = relu(y@Wg+bg), cross = relu(y@Wc+bc),
//                  f2g gather (never materialized),
//                  p2d = (gate*f2g)@Wp, cross2d = (cross*f2g)@Wp.
// 16 rows per block; gate/cross tiles live in LDS.
// ---------------------------------------------------------------------------
__global__ __launch_bounds__(256) void gate_cross_kernel(
    const float* __restrict__ y3d, const float* __restrict__ f2d,
    const int* __restrict__ nn_idx,
    const float* __restrict__ Wg, const float* __restrict__ bg,
    const float* __restrict__ Wc, const float* __restrict__ bc,
    const float* __restrict__ Wp,
    float* __restrict__ p2d, float* __restrict__ cross2d)
{
  __shared__ float yS[16][C3];
  __shared__ float g1[16][CP + 1];
  __shared__ float g2[16][CP + 1];
  const int tid = threadIdx.x;
  const int base = blockIdx.x * 16;
  yS[tid >> 4][tid & 15] = y3d[base * C3 + tid];
  __syncthreads();
  for (int e = tid; e < 16 * CP; e += 256) {
    int r = e / CP, c = e - r * CP;
    int idx = nn_idx[base + r];
    float f = (idx >= 0) ? f2d[idx * CP + c] : 0.f;
    float a1 = bg[c], a2 = bc[c];
    #pragma unroll
    for (int ci = 0; ci < C3; ++ci) {
      float yv = yS[r][ci];
      a1 = fmaf(yv, Wg[ci * CP + c], a1);
      a2 = fmaf(yv, Wc[ci * CP + c], a2);
    }
    g1[r][c] = fmaxf(a1, 0.f) * f;
    g2[r][c] = fmaxf(a2, 0.f) * f;
  }
  __syncthreads();
  for (int e = tid; e < 16 * C2; e += 256) {
    int r = e >> 6, j = e & 63;
    float a1 = 0.f, a2 = 0.f;
    for (int c = 0; c < CP; ++c) {
      float wv = Wp[c * C2 + j];                   // lanes: consecutive j -> coalesced
      a1 = fmaf(g1[r][c], wv, a1);
      a2 = fmaf(g2[r][c], wv, a2);
    }
    int row = base + r;
    p2d[row * C2 + j] = a1;
    cross2d[row * C2 + j] = a2;
  }
}

// ---------------------------------------------------------------------------
// Generic subm-conv:  out[i,c] = epilogue( sum_k sum_ci fin[nbr[i,k],ci]*W[k,ci,c] )
// 64 rows per 256-thread block; per-k W slice staged transposed in LDS
// (wS[c][ci], stride CIN+4 keeps reads <=2-way bank aliased = free);
// gathered rows staged in LDS (stride padded when CIN%32==0).
// Register tile: 4 rows x (COUT/16) cols per thread, float4 LDS reads.
// MODE 0: bn_relu    MODE 1: write mix[:,16:] += cross2d    MODE 2: residual relu
// ---------------------------------------------------------------------------
template <int CIN, int COUT, int MODE>
__global__ __launch_bounds__(256) void conv_bn_kernel(
    const float* __restrict__ fin, const int* __restrict__ nbr, int nrows,
    const float* __restrict__ W, const float* __restrict__ gamma,
    const float* __restrict__ beta, const float* __restrict__ res,
    float* __restrict__ out)
{
  constexpr int CINP_F = (CIN % 32 == 0) ? CIN + 4 : CIN;  // 64->68, 80->80
  constexpr int CINP_W = CIN + 4;                          // 64->68, 80->84
  constexpr int NC = COUT / 16;
  __shared__ __align__(16) float fS[64 * CINP_F];
  __shared__ __align__(16) float wS[COUT * CINP_W];
  const int tid = threadIdx.x;
  const int tx = tid & 15, ty = tid >> 4;
  const int base = blockIdx.x * 64;

  float acc[4][NC];
  #pragma unroll
  for (int i = 0; i < 4; ++i)
    #pragma unroll
    for (int j = 0; j < NC; ++j) acc[i][j] = 0.f;

  for (int k = 0; k < KOFF; ++k) {
    __syncthreads();  // previous-iter compute done before LDS overwrite
    const float* Wk = W + (size_t)k * CIN * COUT;
    for (int e = tid; e < CIN * COUT; e += 256) {
      int ci = e / COUT, c = e - ci * COUT;
      wS[c * CINP_W + ci] = Wk[e];                 // transposed store
    }
    for (int e = tid; e < 64 * CIN; e += 256) {
      int r = e / CIN, c = e - r * CIN;
      int row = base + r;
      int idx = (row < nrows) ? nbr[row * KOFF + k] : -1;
      fS[r * CINP_F + c] = (idx >= 0) ? fin[idx * CIN + c] : 0.f;
    }
    __syncthreads();
    for (int ci = 0; ci < CIN; ci += 4) {
      float4 fv[4];
      #pragma unroll
      for (int ri = 0; ri < 4; ++ri)
        fv[ri] = *(const float4*)&fS[(ty + 16 * ri) * CINP_F + ci];
      #pragma unroll
      for (int cj = 0; cj < NC; ++cj) {
        float4 wv = *(const float4*)&wS[(tx + 16 * cj) * CINP_W + ci];
        #pragma unroll
        for (int ri = 0; ri < 4; ++ri) {
          acc[ri][cj] = fmaf(fv[ri].x, wv.x, acc[ri][cj]);
          acc[ri][cj] = fmaf(fv[ri].y, wv.y, acc[ri][cj]);
          acc[ri][cj] = fmaf(fv[ri].z, wv.z, acc[ri][cj]);
          acc[ri][cj] = fmaf(fv[ri].w, wv.w, acc[ri][cj]);
        }
      }
    }
  }

  #pragma unroll
  for (int ri = 0; ri < 4; ++ri) {
    int row = base + ty + 16 * ri;
    if (row >= nrows) continue;
    #pragma unroll
    for (int cj = 0; cj < NC; ++cj) {
      int c = tx + 16 * cj;
      float v = acc[ri][cj];
      if (MODE == 0) {
        out[row * COUT + c] = fmaxf(fmaf(v, gamma[c], beta[c]), 0.f);
      } else if (MODE == 1) {
        // x2d = relu(v*g+b); mix[:,16+c] = x2d + cross2d
        out[row * CM + 16 + c] =
            fmaxf(fmaf(v, gamma[c], beta[c]), 0.f) + res[row * C2 + c];
      } else {
        // relu(v*g + b + residual)
        out[row * COUT + c] =
            fmaxf(fmaf(v, gamma[c], beta[c]) + res[row * COUT + c], 0.f);
      }
    }
  }
}

// ---------------------------------------------------------------------------
extern "C" void kernel_launch(void* const* d_in, const int* in_sizes, int n_in,
                              void* d_out, int out_size, void* d_ws, size_t ws_size,
                              hipStream_t stream) {
  const float* x3d  = (const float*)d_in[0];
  const float* f2d  = (const float*)d_in[1];
  const int*   nn   = (const int*)d_in[2];
  const int*   nbr  = (const int*)d_in[3];
  const int*   nbds = (const int*)d_in[4];
  const float* W3d  = (const float*)d_in[5];
  const float* g3d  = (const float*)d_in[6];
  const float* b3d  = (const float*)d_in[7];
  const float* Wg   = (const float*)d_in[8];
  const float* bg   = (const float*)d_in[9];
  const float* Wc   = (const float*)d_in[10];
  const float* bc   = (const float*)d_in[11];
  const float* Wp   = (const float*)d_in[12];
  const float* W2d  = (const float*)d_in[13];
  const float* g2d  = (const float*)d_in[14];
  const float* b2d  = (const float*)d_in[15];
  const float* Wm1  = (const float*)d_in[16];
  const float* gm1  = (const float*)d_in[17];
  const float* bm1  = (const float*)d_in[18];
  const float* Wm2  = (const float*)d_in[19];
  const float* gm2  = (const float*)d_in[20];
  const float* bm2  = (const float*)d_in[21];
  const float* Wa1  = (const float*)d_in[22];
  const float* ga1  = (const float*)d_in[23];
  const float* ba1  = (const float*)d_in[24];
  const float* Wa2  = (const float*)d_in[25];
  const float* ga2  = (const float*)d_in[26];
  const float* ba2  = (const float*)d_in[27];
  const float* Wds  = (const float*)d_in[28];
  const float* gds  = (const float*)d_in[29];
  const float* bds  = (const float*)d_in[30];

  // Workspace layout (floats). Peak = 30.72M floats = 122.9 MB.
  float* ws       = (float*)d_ws;
  float* y3d      = ws;                              // N*16  [dead after k3]
  float* p2d      = y3d + (size_t)NPTS * C3;         // N*64  [dead after k3]
  float* cross2d  = p2d + (size_t)NPTS * C2;         // N*64  [dead after k3]
  float* mix      = cross2d + (size_t)NPTS * C2;     // N*80  [dead after k5]
  float* tmp1     = mix + (size_t)NPTS * CM;         // N*80  h1, then a1
  float* hbuf     = tmp1 + (size_t)NPTS * CM;        // N*80
  float* abuf     = ws;                              // N*80  reuses y3d+p2d region

  const int gridN  = (NPTS + 63) / 64;
  const int gridND = (NDPTS + 63) / 64;

  conv3d_bnrelu_kernel<<<NPTS / 16, 256, 0, stream>>>(x3d, nbr, W3d, g3d, b3d,
                                                      y3d, mix);
  gate_cross_kernel<<<NPTS / 16, 256, 0, stream>>>(y3d, f2d, nn, Wg, bg, Wc, bc,
                                                   Wp, p2d, cross2d);
  conv_bn_kernel<C2, C2, 1><<<gridN, 256, 0, stream>>>(p2d, nbr, NPTS, W2d, g2d,
                                                       b2d, cross2d, mix);
  conv_bn_kernel<CM, CM, 0><<<gridN, 256, 0, stream>>>(mix, nbr, NPTS, Wm1, gm1,
                                                       bm1, nullptr, tmp1);
  conv_bn_kernel<CM, CM, 2><<<gridN, 256, 0, stream>>>(tmp1, nbr, NPTS, Wm2, gm2,
                                                       bm2, mix, hbuf);
  conv_bn_kernel<CM, CM, 0><<<gridN, 256, 0, stream>>>(hbuf, nbr, NPTS, Wa1, ga1,
                                                       ba1, nullptr, tmp1);
  conv_bn_kernel<CM, CM, 2><<<gridN, 256, 0, stream>>>(tmp1, nbr, NPTS, Wa2, ga2,
                                                       ba2, hbuf, abuf);
  conv_bn_kernel<CM, CO, 0><<<gridND, 256, 0, stream>>>(abuf, nbds, NDPTS, Wds,
                                                        gds, bds, nullptr,
                                                        (float*)d_out);
}

// Round 2
// 2162.140 us; speedup vs baseline: 2.7606x; 2.7606x over previous
//
#include <hip/hip_runtime.h>

#define NPTS 80000
#define MPTS 150000
#define NDPTS 10000
#define KOFF 27
#define C3 16
#define CP 259
#define C2 64
#define CM 80
#define CO 96

typedef __attribute__((ext_vector_type(8))) short short8;
typedef __attribute__((ext_vector_type(4))) float f32x4;

__device__ inline short bf16r(float f) {
  union { float f; unsigned u; } x{f};
  unsigned r = (x.u + 0x7fffu + ((x.u >> 16) & 1u)) >> 16;
  return (short)r;
}

// ---------------------------------------------------------------------------
// Weight prep: W[k][ci][n] fp32 -> Wbf[k][n][ci_pad] bf16 (transposed, ci
// zero-padded to KC32). Tiny, runs once per launch per weight tensor.
// ---------------------------------------------------------------------------
__global__ void wprep_kernel(const float* __restrict__ W, short* __restrict__ Wbf,
                             int CIN, int COUT_, int KC32) {
  int i = blockIdx.x * 256 + threadIdx.x;
  int total = KOFF * COUT_ * KC32;
  if (i >= total) return;
  int ci = i % KC32;
  int rest = i / KC32;
  int n = rest % COUT_;
  int kk = rest / COUT_;
  float v = (ci < CIN) ? W[((size_t)kk * CIN + ci) * COUT_ + n] : 0.f;
  Wbf[i] = bf16r(v);
}

// ---------------------------------------------------------------------------
// Kernel 1: conv3d (16->16) + bn_relu. Writes y3d (fp32), mix[:, :16] (fp32)
// and mixbf[:, :16] (bf16).
// ---------------------------------------------------------------------------
__global__ __launch_bounds__(256) void conv3d_bnrelu_kernel(
    const float* __restrict__ x3d, const int* __restrict__ nbr,
    const float* __restrict__ W3d, const float* __restrict__ g3d,
    const float* __restrict__ b3d, float* __restrict__ y3d,
    float* __restrict__ mix, short* __restrict__ mixbf)
{
  __shared__ float wS[KOFF * C3 * C3];
  __shared__ float fS[16][C3];
  const int tid = threadIdx.x;
  const int base = blockIdx.x * 16;
  for (int e = tid; e < KOFF * C3 * C3; e += 256) wS[e] = W3d[e];
  const int r = tid >> 4, c = tid & 15;
  const int row = base + r;
  float acc = 0.f;
  for (int k = 0; k < KOFF; ++k) {
    int idx = nbr[row * KOFF + k];
    float fv = (idx >= 0) ? x3d[idx * C3 + c] : 0.f;
    __syncthreads();
    fS[r][c] = fv;
    __syncthreads();
    const float* wk = &wS[k * C3 * C3];
    #pragma unroll
    for (int ci = 0; ci < C3; ++ci)
      acc = fmaf(fS[r][ci], wk[ci * C3 + c], acc);
  }
  float v = fmaxf(fmaf(acc, g3d[c], b3d[c]), 0.f);
  y3d[row * C3 + c] = v;
  mix[row * CM + c] = v;
  mixbf[row * CM + c] = bf16r(v);
}

// ---------------------------------------------------------------------------
// Kernel 2: gate/cross fusion. p2d stored as bf16 (feeds conv2d gather only),
// cross2d stored fp32 (coalesced epilogue read).
// ---------------------------------------------------------------------------
__global__ __launch_bounds__(256) void gate_cross_kernel(
    const float* __restrict__ y3d, const float* __restrict__ f2d,
    const int* __restrict__ nn_idx,
    const float* __restrict__ Wg, const float* __restrict__ bg,
    const float* __restrict__ Wc, const float* __restrict__ bc,
    const float* __restrict__ Wp,
    short* __restrict__ p2dbf, float* __restrict__ cross2d)
{
  __shared__ float yS[16][C3];
  __shared__ float g1[16][CP + 1];
  __shared__ float g2[16][CP + 1];
  const int tid = threadIdx.x;
  const int base = blockIdx.x * 16;
  yS[tid >> 4][tid & 15] = y3d[base * C3 + tid];
  __syncthreads();
  for (int e = tid; e < 16 * CP; e += 256) {
    int r = e / CP, c = e - r * CP;
    int idx = nn_idx[base + r];
    float f = (idx >= 0) ? f2d[idx * CP + c] : 0.f;
    float a1 = bg[c], a2 = bc[c];
    #pragma unroll
    for (int ci = 0; ci < C3; ++ci) {
      float yv = yS[r][ci];
      a1 = fmaf(yv, Wg[ci * CP + c], a1);
      a2 = fmaf(yv, Wc[ci * CP + c], a2);
    }
    g1[r][c] = fmaxf(a1, 0.f) * f;
    g2[r][c] = fmaxf(a2, 0.f) * f;
  }
  __syncthreads();
  for (int e = tid; e < 16 * C2; e += 256) {
    int r = e >> 6, j = e & 63;
    float a1 = 0.f, a2 = 0.f;
    for (int c = 0; c < CP; ++c) {
      float wv = Wp[c * C2 + j];
      a1 = fmaf(g1[r][c], wv, a1);
      a2 = fmaf(g2[r][c], wv, a2);
    }
    int row = base + r;
    p2dbf[row * C2 + j] = bf16r(a1);
    cross2d[row * C2 + j] = a2;
  }
}

// ---------------------------------------------------------------------------
// MFMA subm-conv.  finbf: bf16 activations [nrows][CIN].
// Wbf: [27][COUT][KC*32] bf16 pre-transposed+padded.
// Block: ROWS rows, 4 waves; wave = (ROWS/64) m-tiles x (COUT/16) n-tiles.
// LDS A stride = KC*32+8 bf16 (breaks power-of-2 bank stride).
// MFMA: f32_16x16x32_bf16. A frag: m=lane&15, k=quad*8+j (HW-verified m120).
// C/D: col=lane&15, row=quad*4+reg (HW-verified m89/m91).
// MODE 0: bn_relu -> fp32 out
// MODE 1: bn_relu -> bf16 out
// MODE 2: x2d=bn_relu; v=x2d+res(stride 64); out fp32 mix[:,16+c] + bf16 mixbf
// MODE 3: v=relu(bn+res); out fp32 + bf16
// MODE 4: v=relu(bn+res); out bf16 only
// ---------------------------------------------------------------------------
template <int CIN, int COUT_, int KC, int ROWS, int MODE>
__global__ __launch_bounds__(256) void conv_mfma_kernel(
    const short* __restrict__ finbf, const int* __restrict__ nbr, int nrows,
    const short* __restrict__ Wbf, const float* __restrict__ gamma,
    const float* __restrict__ beta, const float* __restrict__ resf,
    float* __restrict__ outf, short* __restrict__ outbf)
{
  constexpr int KC32 = KC * 32;
  constexpr int AS = KC32 + 8;          // LDS row stride in bf16 (16B aligned)
  constexpr int NT = COUT_ / 16;        // n-tiles
  constexpr int MT = ROWS / 64;         // m-tiles per wave
  constexpr int DCH = CIN / 8;          // data chunks per row
  constexpr int PCH = KC32 / 8;         // padded chunks per row

  __shared__ short fA[ROWS * AS];
  __shared__ short wB[COUT_ * AS];

  const int tid = threadIdx.x;
  const int lane = tid & 63;
  const int w = tid >> 6;
  const int lm = lane & 15;
  const int quad = lane >> 4;
  const int base = blockIdx.x * ROWS;

  f32x4 acc[MT][NT];
  #pragma unroll
  for (int i = 0; i < MT; ++i)
    #pragma unroll
    for (int t = 0; t < NT; ++t) {
      f32x4 z = {0.f, 0.f, 0.f, 0.f};
      acc[i][t] = z;
    }

  for (int k = 0; k < KOFF; ++k) {
    __syncthreads();   // previous-iteration fragment reads complete
    // ---- stage gathered A rows (bf16, zero-padded) ----
    for (int j = tid; j < ROWS * PCH; j += 256) {
      int r = j / PCH, c = j - r * PCH;
      short8 v = {0, 0, 0, 0, 0, 0, 0, 0};
      if (c < DCH) {
        int row = base + r;
        int idx = (row < nrows) ? nbr[row * KOFF + k] : -1;
        if (idx >= 0)
          v = *(const short8*)&finbf[(size_t)idx * CIN + c * 8];
      }
      *(short8*)&fA[r * AS + c * 8] = v;
    }
    // ---- stage W_k (already transposed+padded bf16) ----
    for (int j = tid; j < COUT_ * PCH; j += 256) {
      int n = j / PCH, c = j - n * PCH;
      *(short8*)&wB[n * AS + c * 8] =
          *(const short8*)&Wbf[((size_t)k * COUT_ + n) * KC32 + c * 8];
    }
    __syncthreads();
    // ---- MFMA over K chunks ----
    #pragma unroll
    for (int q = 0; q < KC; ++q) {
      short8 af[MT], bfr[NT];
      #pragma unroll
      for (int i = 0; i < MT; ++i)
        af[i] = *(const short8*)&fA[((w * MT + i) * 16 + lm) * AS + q * 32 + quad * 8];
      #pragma unroll
      for (int t = 0; t < NT; ++t)
        bfr[t] = *(const short8*)&wB[(t * 16 + lm) * AS + q * 32 + quad * 8];
      #pragma unroll
      for (int i = 0; i < MT; ++i)
        #pragma unroll
        for (int t = 0; t < NT; ++t)
          acc[i][t] = __builtin_amdgcn_mfma_f32_16x16x32_bf16(af[i], bfr[t],
                                                              acc[i][t], 0, 0, 0);
    }
  }

  // ---- epilogue ----
  #pragma unroll
  for (int i = 0; i < MT; ++i) {
    int rbase = base + (w * MT + i) * 16 + quad * 4;
    #pragma unroll
    for (int t = 0; t < NT; ++t) {
      int c = t * 16 + lm;
      float g = gamma[c], b = beta[c];
      #pragma unroll
      for (int rg = 0; rg < 4; ++rg) {
        int row = rbase + rg;
        if (row >= nrows) continue;
        float v = acc[i][t][rg];
        if (MODE == 0) {
          outf[(size_t)row * COUT_ + c] = fmaxf(fmaf(v, g, b), 0.f);
        } else if (MODE == 1) {
          outbf[(size_t)row * COUT_ + c] = bf16r(fmaxf(fmaf(v, g, b), 0.f));
        } else if (MODE == 2) {
          float o = fmaxf(fmaf(v, g, b), 0.f) + resf[(size_t)row * C2 + c];
          outf[(size_t)row * CM + 16 + c] = o;
          outbf[(size_t)row * CM + 16 + c] = bf16r(o);
        } else if (MODE == 3) {
          float o = fmaxf(fmaf(v, g, b) + resf[(size_t)row * COUT_ + c], 0.f);
          outf[(size_t)row * COUT_ + c] = o;
          outbf[(size_t)row * COUT_ + c] = bf16r(o);
        } else {
          float o = fmaxf(fmaf(v, g, b) + resf[(size_t)row * COUT_ + c], 0.f);
          outbf[(size_t)row * COUT_ + c] = bf16r(o);
        }
      }
    }
  }
}

// ---------------------------------------------------------------------------
extern "C" void kernel_launch(void* const* d_in, const int* in_sizes, int n_in,
                              void* d_out, int out_size, void* d_ws, size_t ws_size,
                              hipStream_t stream) {
  const float* x3d  = (const float*)d_in[0];
  const float* f2d  = (const float*)d_in[1];
  const int*   nn   = (const int*)d_in[2];
  const int*   nbr  = (const int*)d_in[3];
  const int*   nbds = (const int*)d_in[4];
  const float* W3d  = (const float*)d_in[5];
  const float* g3d  = (const float*)d_in[6];
  const float* b3d  = (const float*)d_in[7];
  const float* Wg   = (const float*)d_in[8];
  const float* bg   = (const float*)d_in[9];
  const float* Wc   = (const float*)d_in[10];
  const float* bc   = (const float*)d_in[11];
  const float* Wp   = (const float*)d_in[12];
  const float* W2d  = (const float*)d_in[13];
  const float* g2d  = (const float*)d_in[14];
  const float* b2d  = (const float*)d_in[15];
  const float* Wm1  = (const float*)d_in[16];
  const float* gm1  = (const float*)d_in[17];
  const float* bm1  = (const float*)d_in[18];
  const float* Wm2  = (const float*)d_in[19];
  const float* gm2  = (const float*)d_in[20];
  const float* bm2  = (const float*)d_in[21];
  const float* Wa1  = (const float*)d_in[22];
  const float* ga1  = (const float*)d_in[23];
  const float* ba1  = (const float*)d_in[24];
  const float* Wa2  = (const float*)d_in[25];
  const float* ga2  = (const float*)d_in[26];
  const float* ba2  = (const float*)d_in[27];
  const float* Wds  = (const float*)d_in[28];
  const float* gds  = (const float*)d_in[29];
  const float* bds  = (const float*)d_in[30];

  const size_t N = NPTS;
  float* ws = (float*)d_ws;
  // fp32 buffers
  float* y3d     = ws;                    // N*16  (k1->k2; region reused by abufbf at k7)
  short* p2dbf   = (short*)(ws + N * 16); // N*64 bf16 = N*32 f  (k2->k3)
  float* cross2d = ws + N * 48;           // N*64  (k2->k3)
  float* mix     = ws + N * 112;          // N*80  (k1,k3 -> k5 residual)
  short* mixbf   = (short*)(ws + N * 192);// N*80 bf16 (k1,k3 -> k4)
  short* tmp1bf  = (short*)(ws + N * 232);// N*80 bf16 (k4->k5, reused k6->k7)
  float* hbuf    = ws + N * 272;          // N*80  (k5->k7 residual)
  short* hbufbf  = (short*)(ws + N * 352);// N*80 bf16 (k5->k6)
  short* abufbf  = (short*)ws;            // N*80 bf16 (k7->k8), reuses y3d+p2dbf
  // weight bf16 buffers at tail
  short* wtail   = (short*)(ws + N * 392);
  short* Wbf2d = wtail;                    // 27*64*64
  short* Wbfm1 = Wbf2d + 27 * 64 * 64;     // 27*80*96
  short* Wbfm2 = Wbfm1 + 27 * 80 * 96;
  short* Wbfa1 = Wbfm2 + 27 * 80 * 96;
  short* Wbfa2 = Wbfa1 + 27 * 80 * 96;
  short* Wbfds = Wbfa2 + 27 * 80 * 96;     // 27*96*96

  // ---- weight prep (bf16 transpose+pad) ----
  {
    int t2d = KOFF * 64 * 64;
    wprep_kernel<<<(t2d + 255) / 256, 256, 0, stream>>>(W2d, Wbf2d, 64, 64, 64);
    int tcm = KOFF * 80 * 96;
    wprep_kernel<<<(tcm + 255) / 256, 256, 0, stream>>>(Wm1, Wbfm1, 80, 80, 96);
    wprep_kernel<<<(tcm + 255) / 256, 256, 0, stream>>>(Wm2, Wbfm2, 80, 80, 96);
    wprep_kernel<<<(tcm + 255) / 256, 256, 0, stream>>>(Wa1, Wbfa1, 80, 80, 96);
    wprep_kernel<<<(tcm + 255) / 256, 256, 0, stream>>>(Wa2, Wbfa2, 80, 80, 96);
    int tds = KOFF * 96 * 96;
    wprep_kernel<<<(tds + 255) / 256, 256, 0, stream>>>(Wds, Wbfds, 80, 96, 96);
  }

  conv3d_bnrelu_kernel<<<NPTS / 16, 256, 0, stream>>>(x3d, nbr, W3d, g3d, b3d,
                                                      y3d, mix, mixbf);
  gate_cross_kernel<<<NPTS / 16, 256, 0, stream>>>(y3d, f2d, nn, Wg, bg, Wc, bc,
                                                   Wp, p2dbf, cross2d);

  const int gridN = (NPTS + 255) / 256;
  conv_mfma_kernel<64, 64, 2, 256, 2><<<gridN, 256, 0, stream>>>(
      p2dbf, nbr, NPTS, Wbf2d, g2d, b2d, cross2d, mix, mixbf);
  conv_mfma_kernel<80, 80, 3, 256, 1><<<gridN, 256, 0, stream>>>(
      mixbf, nbr, NPTS, Wbfm1, gm1, bm1, nullptr, nullptr, tmp1bf);
  conv_mfma_kernel<80, 80, 3, 256, 3><<<gridN, 256, 0, stream>>>(
      tmp1bf, nbr, NPTS, Wbfm2, gm2, bm2, mix, hbuf, hbufbf);
  conv_mfma_kernel<80, 80, 3, 256, 1><<<gridN, 256, 0, stream>>>(
      hbufbf, nbr, NPTS, Wbfa1, ga1, ba1, nullptr, nullptr, tmp1bf);
  conv_mfma_kernel<80, 80, 3, 256, 4><<<gridN, 256, 0, stream>>>(
      tmp1bf, nbr, NPTS, Wbfa2, ga2, ba2, hbuf, nullptr, abufbf);

  const int gridND = (NDPTS + 63) / 64;
  conv_mfma_kernel<80, 96, 3, 64, 0><<<gridND, 256, 0, stream>>>(
      abufbf, nbds, NDPTS, Wbfds, gds, bds, nullptr, (float*)d_out, nullptr);
}

// Round 3
// 1921.137 us; speedup vs baseline: 3.1070x; 1.1254x over previous
//
#include <hip/hip_runtime.h>

#define NPTS 80000
#define MPTS 150000
#define NDPTS 10000
#define KOFF 27
#define C3 16
#define CP 259
#define C2 64
#define CM 80
#define CO 96

typedef __attribute__((ext_vector_type(8))) short short8;
typedef __attribute__((ext_vector_type(4))) float f32x4;

__device__ inline short bf16r(float f) {
  union { float f; unsigned u; } x{f};
  unsigned r = (x.u + 0x7fffu + ((x.u >> 16) & 1u)) >> 16;
  return (short)r;
}

// ---------------------------------------------------------------------------
// Weight prep: W[k][ci][n] fp32 -> Wbf[k][n][ci_pad] bf16 (transposed, ci
// zero-padded to KC32). Tiny, runs once per launch per weight tensor.
// ---------------------------------------------------------------------------
__global__ void wprep_kernel(const float* __restrict__ W, short* __restrict__ Wbf,
                             int CIN, int COUT_, int KC32) {
  int i = blockIdx.x * 256 + threadIdx.x;
  int total = KOFF * COUT_ * KC32;
  if (i >= total) return;
  int ci = i % KC32;
  int rest = i / KC32;
  int n = rest % COUT_;
  int kk = rest / COUT_;
  float v = (ci < CIN) ? W[((size_t)kk * CIN + ci) * COUT_ + n] : 0.f;
  Wbf[i] = bf16r(v);
}

// ---------------------------------------------------------------------------
// Wp prep: fp32 [259][64] -> bf16 fragment-ordered [q][t][lane][8], K padded
// to 288 (9 chunks of 32). B-frag layout: n = t*16 + (lane&15),
// k = q*32 + (lane>>4)*8 + j  (HW-verified 16x16x32 operand layout).
// ---------------------------------------------------------------------------
__global__ void wpfrag_kernel(const float* __restrict__ Wp, short* __restrict__ WpF) {
  int i = blockIdx.x * 256 + threadIdx.x;
  if (i >= 9 * 4 * 64 * 8) return;
  int j = i & 7, lane = (i >> 3) & 63, t = (i >> 9) & 3, q = i >> 11;
  int k = q * 32 + (lane >> 4) * 8 + j;
  int n = t * 16 + (lane & 15);
  WpF[i] = (k < CP) ? bf16r(Wp[(size_t)k * C2 + n]) : (short)0;
}

// ---------------------------------------------------------------------------
// Kernel 1: conv3d (16->16) + bn_relu. Writes y3d (fp32), mix[:, :16] (fp32)
// and mixbf[:, :16] (bf16).
// ---------------------------------------------------------------------------
__global__ __launch_bounds__(256) void conv3d_bnrelu_kernel(
    const float* __restrict__ x3d, const int* __restrict__ nbr,
    const float* __restrict__ W3d, const float* __restrict__ g3d,
    const float* __restrict__ b3d, float* __restrict__ y3d,
    float* __restrict__ mix, short* __restrict__ mixbf)
{
  __shared__ float wS[KOFF * C3 * C3];
  __shared__ float fS[16][C3];
  const int tid = threadIdx.x;
  const int base = blockIdx.x * 16;
  for (int e = tid; e < KOFF * C3 * C3; e += 256) wS[e] = W3d[e];
  const int r = tid >> 4, c = tid & 15;
  const int row = base + r;
  float acc = 0.f;
  for (int k = 0; k < KOFF; ++k) {
    int idx = nbr[row * KOFF + k];
    float fv = (idx >= 0) ? x3d[idx * C3 + c] : 0.f;
    __syncthreads();
    fS[r][c] = fv;
    __syncthreads();
    const float* wk = &wS[k * C3 * C3];
    #pragma unroll
    for (int ci = 0; ci < C3; ++ci)
      acc = fmaf(fS[r][ci], wk[ci * C3 + c], acc);
  }
  float v = fmaxf(fmaf(acc, g3d[c], b3d[c]), 0.f);
  y3d[row * C3 + c] = v;
  mix[row * CM + c] = v;
  mixbf[row * CM + c] = bf16r(v);
}

// ---------------------------------------------------------------------------
// Kernel 2 (rewritten): gate/cross fusion.
// Phase 1: thread owns column c; Wg/Wc columns register-cached (64 VGPRs);
//          y3d rows via wave-uniform scalar loads; f2d reads coalesced.
//          g1 = bf16(relu(y@Wg+bg)*f2g), g2 = bf16(relu(y@Wc+bc)*f2g) -> LDS.
// Phase 2: MFMA [32 x 288] x [288 x 64] for both g1 (->p2d bf16) and
//          g2 (->cross2d fp32). Wave = (gsel, m-tile). B frags from
//          fragment-ordered global WpF (coalesced).
// Block = 32 rows, LDS 37.9 KB -> 4 blocks/CU.
// ---------------------------------------------------------------------------
__global__ __launch_bounds__(256) void gate_cross_mfma_kernel(
    const float* __restrict__ y3d, const float* __restrict__ f2d,
    const int* __restrict__ nn_idx,
    const float* __restrict__ Wg, const float* __restrict__ bg,
    const float* __restrict__ Wc, const float* __restrict__ bc,
    const short* __restrict__ WpF,
    short* __restrict__ p2dbf, float* __restrict__ cross2d)
{
  constexpr int RS = 296;  // LDS row stride in shorts = 148 dwords -> <=2-way
  __shared__ short g1S[32 * RS];
  __shared__ short g2S[32 * RS];
  const int tid = threadIdx.x;
  const int lane = tid & 63;
  const int w = tid >> 6;
  const int lm = lane & 15;
  const int quad = lane >> 4;
  const int base = blockIdx.x * 32;

  // zero the K-pad columns 259..287
  for (int e = tid; e < 32 * 32; e += 256) {
    int r = e >> 5, cc = 256 + (e & 31);
    if (cc >= CP) {
      g1S[r * RS + cc] = 0;
      g2S[r * RS + cc] = 0;
    }
  }

  // ---- phase 1: cols 0..255 (one col per thread) ----
  {
    const int c = tid;
    float wg[16], wc[16];
    #pragma unroll
    for (int ci = 0; ci < 16; ++ci) {
      wg[ci] = Wg[ci * CP + c];
      wc[ci] = Wc[ci * CP + c];
    }
    const float bgv = bg[c], bcv = bc[c];
    for (int r = 0; r < 32; ++r) {
      const int row = base + r;
      const int idx = nn_idx[row];                    // uniform -> s_load
      const float* yr = y3d + (size_t)row * C3;       // uniform base
      float f = (idx >= 0) ? f2d[(size_t)idx * CP + c] : 0.f;
      float a1 = bgv, a2 = bcv;
      #pragma unroll
      for (int ci = 0; ci < 16; ++ci) {
        float yv = yr[ci];                            // scalar load
        a1 = fmaf(yv, wg[ci], a1);
        a2 = fmaf(yv, wc[ci], a2);
      }
      g1S[r * RS + c] = bf16r(fmaxf(a1, 0.f) * f);
      g2S[r * RS + c] = bf16r(fmaxf(a2, 0.f) * f);
    }
  }
  // ---- phase 1 tail: cols 256..258 (3 lanes of wave 0) ----
  if (w == 0 && lane < 3) {
    const int c = 256 + lane;
    float wg[16], wc[16];
    #pragma unroll
    for (int ci = 0; ci < 16; ++ci) {
      wg[ci] = Wg[ci * CP + c];
      wc[ci] = Wc[ci * CP + c];
    }
    const float bgv = bg[c], bcv = bc[c];
    for (int r = 0; r < 32; ++r) {
      const int row = base + r;
      const int idx = nn_idx[row];
      const float* yr = y3d + (size_t)row * C3;
      float f = (idx >= 0) ? f2d[(size_t)idx * CP + c] : 0.f;
      float a1 = bgv, a2 = bcv;
      #pragma unroll
      for (int ci = 0; ci < 16; ++ci) {
        float yv = yr[ci];
        a1 = fmaf(yv, wg[ci], a1);
        a2 = fmaf(yv, wc[ci], a2);
      }
      g1S[r * RS + c] = bf16r(fmaxf(a1, 0.f) * f);
      g2S[r * RS + c] = bf16r(fmaxf(a2, 0.f) * f);
    }
  }
  __syncthreads();

  // ---- phase 2: MFMA. wave -> (gsel = w&1, m-tile = w>>1) ----
  const int gsel = w & 1;
  const int mt = w >> 1;
  const short* gS = gsel ? g2S : g1S;
  f32x4 acc[4];
  #pragma unroll
  for (int t = 0; t < 4; ++t) {
    f32x4 z = {0.f, 0.f, 0.f, 0.f};
    acc[t] = z;
  }
  #pragma unroll
  for (int q = 0; q < 9; ++q) {
    short8 af = *(const short8*)&gS[(mt * 16 + lm) * RS + q * 32 + quad * 8];
    #pragma unroll
    for (int t = 0; t < 4; ++t) {
      short8 bf = *(const short8*)&WpF[(((q * 4 + t) * 64) + lane) * 8];
      acc[t] = __builtin_amdgcn_mfma_f32_16x16x32_bf16(af, bf, acc[t], 0, 0, 0);
    }
  }
  #pragma unroll
  for (int t = 0; t < 4; ++t) {
    const int c = t * 16 + lm;
    #pragma unroll
    for (int rg = 0; rg < 4; ++rg) {
      const int row = base + mt * 16 + quad * 4 + rg;
      float v = acc[t][rg];
      if (gsel == 0)
        p2dbf[(size_t)row * C2 + c] = bf16r(v);
      else
        cross2d[(size_t)row * C2 + c] = v;
    }
  }
}

// ---------------------------------------------------------------------------
// MFMA subm-conv.  finbf: bf16 activations [nrows][CIN].
// Wbf: [27][COUT][KC*32] bf16 pre-transposed+padded.
// Block: ROWS rows, 4 waves; wave = (ROWS/64) m-tiles x (COUT/16) n-tiles.
// LDS A stride = KC*32+8 bf16 (breaks power-of-2 bank stride).
// MFMA: f32_16x16x32_bf16. A frag: m=lane&15, k=quad*8+j.
// C/D: col=lane&15, row=quad*4+reg.
// MODE 0: bn_relu -> fp32 out
// MODE 1: bn_relu -> bf16 out
// MODE 2: x2d=bn_relu; v=x2d+res(stride 64); out fp32 mix[:,16+c] + bf16 mixbf
// MODE 3: v=relu(bn+res); out fp32 + bf16
// MODE 4: v=relu(bn+res); out bf16 only
// ---------------------------------------------------------------------------
template <int CIN, int COUT_, int KC, int ROWS, int MODE>
__global__ __launch_bounds__(256) void conv_mfma_kernel(
    const short* __restrict__ finbf, const int* __restrict__ nbr, int nrows,
    const short* __restrict__ Wbf, const float* __restrict__ gamma,
    const float* __restrict__ beta, const float* __restrict__ resf,
    float* __restrict__ outf, short* __restrict__ outbf)
{
  constexpr int KC32 = KC * 32;
  constexpr int AS = KC32 + 8;          // LDS row stride in bf16 (16B aligned)
  constexpr int NT = COUT_ / 16;        // n-tiles
  constexpr int MT = ROWS / 64;         // m-tiles per wave
  constexpr int DCH = CIN / 8;          // data chunks per row
  constexpr int PCH = KC32 / 8;         // padded chunks per row

  __shared__ short fA[ROWS * AS];
  __shared__ short wB[COUT_ * AS];

  const int tid = threadIdx.x;
  const int lane = tid & 63;
  const int w = tid >> 6;
  const int lm = lane & 15;
  const int quad = lane >> 4;
  const int base = blockIdx.x * ROWS;

  f32x4 acc[MT][NT];
  #pragma unroll
  for (int i = 0; i < MT; ++i)
    #pragma unroll
    for (int t = 0; t < NT; ++t) {
      f32x4 z = {0.f, 0.f, 0.f, 0.f};
      acc[i][t] = z;
    }

  for (int k = 0; k < KOFF; ++k) {
    __syncthreads();   // previous-iteration fragment reads complete
    // ---- stage gathered A rows (bf16, zero-padded) ----
    for (int j = tid; j < ROWS * PCH; j += 256) {
      int r = j / PCH, c = j - r * PCH;
      short8 v = {0, 0, 0, 0, 0, 0, 0, 0};
      if (c < DCH) {
        int row = base + r;
        int idx = (row < nrows) ? nbr[row * KOFF + k] : -1;
        if (idx >= 0)
          v = *(const short8*)&finbf[(size_t)idx * CIN + c * 8];
      }
      *(short8*)&fA[r * AS + c * 8] = v;
    }
    // ---- stage W_k (already transposed+padded bf16) ----
    for (int j = tid; j < COUT_ * PCH; j += 256) {
      int n = j / PCH, c = j - n * PCH;
      *(short8*)&wB[n * AS + c * 8] =
          *(const short8*)&Wbf[((size_t)k * COUT_ + n) * KC32 + c * 8];
    }
    __syncthreads();
    // ---- MFMA over K chunks ----
    #pragma unroll
    for (int q = 0; q < KC; ++q) {
      short8 af[MT], bfr[NT];
      #pragma unroll
      for (int i = 0; i < MT; ++i)
        af[i] = *(const short8*)&fA[((w * MT + i) * 16 + lm) * AS + q * 32 + quad * 8];
      #pragma unroll
      for (int t = 0; t < NT; ++t)
        bfr[t] = *(const short8*)&wB[(t * 16 + lm) * AS + q * 32 + quad * 8];
      #pragma unroll
      for (int i = 0; i < MT; ++i)
        #pragma unroll
        for (int t = 0; t < NT; ++t)
          acc[i][t] = __builtin_amdgcn_mfma_f32_16x16x32_bf16(af[i], bfr[t],
                                                              acc[i][t], 0, 0, 0);
    }
  }

  // ---- epilogue ----
  #pragma unroll
  for (int i = 0; i < MT; ++i) {
    int rbase = base + (w * MT + i) * 16 + quad * 4;
    #pragma unroll
    for (int t = 0; t < NT; ++t) {
      int c = t * 16 + lm;
      float g = gamma[c], b = beta[c];
      #pragma unroll
      for (int rg = 0; rg < 4; ++rg) {
        int row = rbase + rg;
        if (row >= nrows) continue;
        float v = acc[i][t][rg];
        if (MODE == 0) {
          outf[(size_t)row * COUT_ + c] = fmaxf(fmaf(v, g, b), 0.f);
        } else if (MODE == 1) {
          outbf[(size_t)row * COUT_ + c] = bf16r(fmaxf(fmaf(v, g, b), 0.f));
        } else if (MODE == 2) {
          float o = fmaxf(fmaf(v, g, b), 0.f) + resf[(size_t)row * C2 + c];
          outf[(size_t)row * CM + 16 + c] = o;
          outbf[(size_t)row * CM + 16 + c] = bf16r(o);
        } else if (MODE == 3) {
          float o = fmaxf(fmaf(v, g, b) + resf[(size_t)row * COUT_ + c], 0.f);
          outf[(size_t)row * COUT_ + c] = o;
          outbf[(size_t)row * COUT_ + c] = bf16r(o);
        } else {
          float o = fmaxf(fmaf(v, g, b) + resf[(size_t)row * COUT_ + c], 0.f);
          outbf[(size_t)row * COUT_ + c] = bf16r(o);
        }
      }
    }
  }
}

// ---------------------------------------------------------------------------
extern "C" void kernel_launch(void* const* d_in, const int* in_sizes, int n_in,
                              void* d_out, int out_size, void* d_ws, size_t ws_size,
                              hipStream_t stream) {
  const float* x3d  = (const float*)d_in[0];
  const float* f2d  = (const float*)d_in[1];
  const int*   nn   = (const int*)d_in[2];
  const int*   nbr  = (const int*)d_in[3];
  const int*   nbds = (const int*)d_in[4];
  const float* W3d  = (const float*)d_in[5];
  const float* g3d  = (const float*)d_in[6];
  const float* b3d  = (const float*)d_in[7];
  const float* Wg   = (const float*)d_in[8];
  const float* bg   = (const float*)d_in[9];
  const float* Wc   = (const float*)d_in[10];
  const float* bc   = (const float*)d_in[11];
  const float* Wp   = (const float*)d_in[12];
  const float* W2d  = (const float*)d_in[13];
  const float* g2d  = (const float*)d_in[14];
  const float* b2d  = (const float*)d_in[15];
  const float* Wm1  = (const float*)d_in[16];
  const float* gm1  = (const float*)d_in[17];
  const float* bm1  = (const float*)d_in[18];
  const float* Wm2  = (const float*)d_in[19];
  const float* gm2  = (const float*)d_in[20];
  const float* bm2  = (const float*)d_in[21];
  const float* Wa1  = (const float*)d_in[22];
  const float* ga1  = (const float*)d_in[23];
  const float* ba1  = (const float*)d_in[24];
  const float* Wa2  = (const float*)d_in[25];
  const float* ga2  = (const float*)d_in[26];
  const float* ba2  = (const float*)d_in[27];
  const float* Wds  = (const float*)d_in[28];
  const float* gds  = (const float*)d_in[29];
  const float* bds  = (const float*)d_in[30];

  const size_t N = NPTS;
  float* ws = (float*)d_ws;
  // fp32 buffers
  float* y3d     = ws;                    // N*16  (k1->k2; region reused by abufbf at k7)
  short* p2dbf   = (short*)(ws + N * 16); // N*64 bf16 = N*32 f  (k2->k3)
  float* cross2d = ws + N * 48;           // N*64  (k2->k3)
  float* mix     = ws + N * 112;          // N*80  (k1,k3 -> k5 residual)
  short* mixbf   = (short*)(ws + N * 192);// N*80 bf16 (k1,k3 -> k4)
  short* tmp1bf  = (short*)(ws + N * 232);// N*80 bf16 (k4->k5, reused k6->k7)
  float* hbuf    = ws + N * 272;          // N*80  (k5->k7 residual)
  short* hbufbf  = (short*)(ws + N * 352);// N*80 bf16 (k5->k6)
  short* abufbf  = (short*)ws;            // N*80 bf16 (k7->k8), reuses y3d+p2dbf
  // weight bf16 buffers at tail
  short* wtail   = (short*)(ws + N * 392);
  short* Wbf2d = wtail;                    // 27*64*64
  short* Wbfm1 = Wbf2d + 27 * 64 * 64;     // 27*80*96
  short* Wbfm2 = Wbfm1 + 27 * 80 * 96;
  short* Wbfa1 = Wbfm2 + 27 * 80 * 96;
  short* Wbfa2 = Wbfa1 + 27 * 80 * 96;
  short* Wbfds = Wbfa2 + 27 * 80 * 96;     // 27*96*96
  short* WpF   = Wbfds + 27 * 96 * 96;     // 9*4*64*8 = 18432 bf16

  // ---- weight prep (bf16 transpose+pad) ----
  {
    int t2d = KOFF * 64 * 64;
    wprep_kernel<<<(t2d + 255) / 256, 256, 0, stream>>>(W2d, Wbf2d, 64, 64, 64);
    int tcm = KOFF * 80 * 96;
    wprep_kernel<<<(tcm + 255) / 256, 256, 0, stream>>>(Wm1, Wbfm1, 80, 80, 96);
    wprep_kernel<<<(tcm + 255) / 256, 256, 0, stream>>>(Wm2, Wbfm2, 80, 80, 96);
    wprep_kernel<<<(tcm + 255) / 256, 256, 0, stream>>>(Wa1, Wbfa1, 80, 80, 96);
    wprep_kernel<<<(tcm + 255) / 256, 256, 0, stream>>>(Wa2, Wbfa2, 80, 80, 96);
    int tds = KOFF * 96 * 96;
    wprep_kernel<<<(tds + 255) / 256, 256, 0, stream>>>(Wds, Wbfds, 80, 96, 96);
    wpfrag_kernel<<<(9 * 4 * 64 * 8 + 255) / 256, 256, 0, stream>>>(Wp, WpF);
  }

  conv3d_bnrelu_kernel<<<NPTS / 16, 256, 0, stream>>>(x3d, nbr, W3d, g3d, b3d,
                                                      y3d, mix, mixbf);
  gate_cross_mfma_kernel<<<NPTS / 32, 256, 0, stream>>>(y3d, f2d, nn, Wg, bg,
                                                        Wc, bc, WpF, p2dbf,
                                                        cross2d);

  const int gridN = (NPTS + 255) / 256;
  conv_mfma_kernel<64, 64, 2, 256, 2><<<gridN, 256, 0, stream>>>(
      p2dbf, nbr, NPTS, Wbf2d, g2d, b2d, cross2d, mix, mixbf);
  conv_mfma_kernel<80, 80, 3, 256, 1><<<gridN, 256, 0, stream>>>(
      mixbf, nbr, NPTS, Wbfm1, gm1, bm1, nullptr, nullptr, tmp1bf);
  conv_mfma_kernel<80, 80, 3, 256, 3><<<gridN, 256, 0, stream>>>(
      tmp1bf, nbr, NPTS, Wbfm2, gm2, bm2, mix, hbuf, hbufbf);
  conv_mfma_kernel<80, 80, 3, 256, 1><<<gridN, 256, 0, stream>>>(
      hbufbf, nbr, NPTS, Wbfa1, ga1, ba1, nullptr, nullptr, tmp1bf);
  conv_mfma_kernel<80, 80, 3, 256, 4><<<gridN, 256, 0, stream>>>(
      tmp1bf, nbr, NPTS, Wbfa2, ga2, ba2, hbuf, nullptr, abufbf);

  const int gridND = (NDPTS + 63) / 64;
  conv_mfma_kernel<80, 96, 3, 64, 0><<<gridND, 256, 0, stream>>>(
      abufbf, nbds, NDPTS, Wbfds, gds, bds, nullptr, (float*)d_out, nullptr);
}